// Round 1
// baseline (2602.679 us; speedup 1.0000x reference)
//
#include <hip/hip_runtime.h>
#include <math.h>

#define N_NODES 10000
#define N_EDGES 20000
#define N_GRAPHS 64
#define DIM 64
#define NFEAT 32
#define EDIM 16
#define NCLS 10

// e = edge_attr @ et_w + et_b : [E,16]@[16,64]
__global__ __launch_bounds__(256) void k_edge_feat(const float* __restrict__ ea,
    const float* __restrict__ w, const float* __restrict__ b,
    float* __restrict__ out) {
  int idx = blockIdx.x * 256 + threadIdx.x;
  if (idx >= N_EDGES * DIM) return;
  int e = idx >> 6, o = idx & 63;
  float a = b[o];
  const float* er = ea + e * EDIM;
  #pragma unroll
  for (int i = 0; i < EDIM; ++i) a = fmaf(er[i], w[i * DIM + o], a);
  out[idx] = a;
}

// h1 = relu(e @ w1 + b1) : [E,64]@[64,128]
__global__ __launch_bounds__(256) void k_mlp1(const float* __restrict__ ef,
    const float* __restrict__ w1, const float* __restrict__ b1,
    float* __restrict__ h1) {
  int idx = blockIdx.x * 256 + threadIdx.x;
  if (idx >= N_EDGES * 128) return;
  int e = idx >> 7, j = idx & 127;
  float a = b1[j];
  const float* er = ef + e * DIM;
  #pragma unroll 8
  for (int i = 0; i < DIM; ++i) a = fmaf(er[i], w1[i * 128 + j], a);
  h1[idx] = fmaxf(a, 0.f);
}

// agg = h @ root + bias (initializes agg before edge scatter)
template<int IN>
__global__ __launch_bounds__(256) void k_root(const float* __restrict__ h,
    const float* __restrict__ root, const float* __restrict__ bias,
    float* __restrict__ agg) {
  int idx = blockIdx.x * 256 + threadIdx.x;
  if (idx >= N_NODES * DIM) return;
  int n = idx >> 6, o = idx & 63;
  float a = bias[o];
  const float* hr = h + n * IN;
  #pragma unroll 8
  for (int i = 0; i < IN; ++i) a = fmaf(hr[i], root[i * DIM + o], a);
  agg[idx] = a;
}

// Fused: msg[e,o] = sum_i x_src[e,i] * (sum_j h1[e,j]*w2[j,i,o] + b2[i,o]);
// atomicAdd into agg[dst[e]]. Block = 64 edges x 64 outs; thread = 4x4 tile.
template<int IN>
__global__ __launch_bounds__(256) void k_msg(const float* __restrict__ h1,
    const float* __restrict__ xin, const int* __restrict__ src,
    const int* __restrict__ dst, const float* __restrict__ w2,
    const float* __restrict__ b2, float* __restrict__ agg) {
  __shared__ float sh_h[64][129];      // +1 pad: stride-129 kills bank conflicts
  __shared__ float sh_x[64][IN + 1];
  const int t = threadIdx.x;
  const int e0 = blockIdx.x * 64;

  for (int idx = t; idx < 64 * 128; idx += 256) {
    int r = idx >> 7, c = idx & 127;
    int e = e0 + r;
    sh_h[r][c] = (e < N_EDGES) ? h1[e * 128 + c] : 0.f;
  }
  for (int idx = t; idx < 64 * IN; idx += 256) {
    int r = idx / IN, c = idx % IN;
    int e = e0 + r;
    sh_x[r][c] = (e < N_EDGES) ? xin[src[e] * IN + c] : 0.f;
  }
  __syncthreads();

  const int og = (t & 15) << 2;   // 4 consecutive output cols
  const int eg = (t >> 4) << 2;   // 4 consecutive edges
  float acc[4][4] = {};

  for (int j = 0; j < 128; ++j) {
    float a[4];
    #pragma unroll
    for (int r = 0; r < 4; ++r) a[r] = sh_h[eg + r][j];
    const float* wrow = w2 + j * (IN * DIM) + og;
    #pragma unroll 8
    for (int i = 0; i < IN; ++i) {
      const float4 w4 = *(const float4*)(wrow + i * DIM);
      #pragma unroll
      for (int r = 0; r < 4; ++r) {
        float p = a[r] * sh_x[eg + r][i];
        acc[r][0] = fmaf(p, w4.x, acc[r][0]);
        acc[r][1] = fmaf(p, w4.y, acc[r][1]);
        acc[r][2] = fmaf(p, w4.z, acc[r][2]);
        acc[r][3] = fmaf(p, w4.w, acc[r][3]);
      }
    }
  }
  // bias term: + sum_i x_src[e,i] * b2[i,o]
  #pragma unroll 8
  for (int i = 0; i < IN; ++i) {
    const float4 b4 = *(const float4*)(b2 + i * DIM + og);
    #pragma unroll
    for (int r = 0; r < 4; ++r) {
      float xv = sh_x[eg + r][i];
      acc[r][0] = fmaf(xv, b4.x, acc[r][0]);
      acc[r][1] = fmaf(xv, b4.y, acc[r][1]);
      acc[r][2] = fmaf(xv, b4.z, acc[r][2]);
      acc[r][3] = fmaf(xv, b4.w, acc[r][3]);
    }
  }
  #pragma unroll
  for (int r = 0; r < 4; ++r) {
    int e = e0 + eg + r;
    if (e < N_EDGES) {
      float* ap = agg + dst[e] * DIM + og;
      atomicAdd(ap + 0, acc[r][0]);
      atomicAdd(ap + 1, acc[r][1]);
      atomicAdd(ap + 2, acc[r][2]);
      atomicAdd(ap + 3, acc[r][3]);
    }
  }
}

// BatchNorm stats (biased var) per channel -> scale/shift. f64 accumulation.
__global__ __launch_bounds__(256) void k_bnstats(const float* __restrict__ agg,
    const float* __restrict__ gamma, const float* __restrict__ beta,
    float* __restrict__ scale, float* __restrict__ shift) {
  int c = blockIdx.x;
  int t = threadIdx.x;
  double s = 0.0, s2 = 0.0;
  for (int n = t; n < N_NODES; n += 256) {
    float v = agg[n * DIM + c];
    s += v;
    s2 += (double)v * v;
  }
  __shared__ double sh0[256];
  __shared__ double sh1[256];
  sh0[t] = s; sh1[t] = s2;
  __syncthreads();
  for (int w = 128; w > 0; w >>= 1) {
    if (t < w) { sh0[t] += sh0[t + w]; sh1[t] += sh1[t + w]; }
    __syncthreads();
  }
  if (t == 0) {
    double m = sh0[0] / N_NODES;
    double v = sh1[0] / N_NODES - m * m;
    float inv = (float)(1.0 / sqrt(v + 1e-5));
    float sc = gamma[c] * inv;
    scale[c] = sc;
    shift[c] = beta[c] - (float)m * sc;
  }
}

// h_out = relu(agg*scale+shift) [+ resid]
__global__ __launch_bounds__(256) void k_bnapply(const float* __restrict__ agg,
    const float* __restrict__ scale, const float* __restrict__ shift,
    const float* __restrict__ resid, float* __restrict__ hout) {
  int idx = blockIdx.x * 256 + threadIdx.x;
  if (idx >= N_NODES * DIM) return;
  int c = idx & 63;
  float v = fmaxf(fmaf(agg[idx], scale[c], shift[c]), 0.f);
  if (resid) v += resid[idx];
  hout[idx] = v;
}

// global_max_pool: h >= 0 so uint-bits atomicMax is order-correct (init 0)
__global__ __launch_bounds__(256) void k_pool(const float* __restrict__ h,
    const int* __restrict__ batch, float* __restrict__ g) {
  int idx = blockIdx.x * 256 + threadIdx.x;
  if (idx >= N_NODES * DIM) return;
  int n = idx >> 6, c = idx & 63;
  atomicMax((unsigned int*)&g[batch[n] * DIM + c], __float_as_uint(h[idx]));
}

// head: relu(g@w1+b1) -> relu(@w2+b2) -> sigmoid(@wo+bo). One block.
__global__ __launch_bounds__(256) void k_head(const float* __restrict__ g,
    const float* __restrict__ w1, const float* __restrict__ b1,
    const float* __restrict__ w2, const float* __restrict__ b2,
    const float* __restrict__ wo, const float* __restrict__ bo,
    float* __restrict__ out) {
  __shared__ float s0[N_GRAPHS * DIM];
  __shared__ float s1[N_GRAPHS * DIM];
  int t = threadIdx.x;
  for (int idx = t; idx < N_GRAPHS * DIM; idx += 256) s0[idx] = g[idx];
  __syncthreads();
  for (int idx = t; idx < N_GRAPHS * DIM; idx += 256) {
    int r = idx >> 6, c = idx & 63;
    float a = b1[c];
    #pragma unroll 8
    for (int i = 0; i < DIM; ++i) a = fmaf(s0[(r << 6) + i], w1[i * DIM + c], a);
    s1[idx] = fmaxf(a, 0.f);
  }
  __syncthreads();
  for (int idx = t; idx < N_GRAPHS * DIM; idx += 256) {
    int r = idx >> 6, c = idx & 63;
    float a = b2[c];
    #pragma unroll 8
    for (int i = 0; i < DIM; ++i) a = fmaf(s1[(r << 6) + i], w2[i * DIM + c], a);
    s0[idx] = fmaxf(a, 0.f);
  }
  __syncthreads();
  for (int idx = t; idx < N_GRAPHS * NCLS; idx += 256) {
    int r = idx / NCLS, c = idx % NCLS;
    float a = bo[c];
    #pragma unroll 8
    for (int i = 0; i < DIM; ++i) a = fmaf(s0[(r << 6) + i], wo[i * NCLS + c], a);
    out[idx] = 1.f / (1.f + expf(-a));
  }
}

extern "C" void kernel_launch(void* const* d_in, const int* in_sizes, int n_in,
                              void* d_out, int out_size, void* d_ws, size_t ws_size,
                              hipStream_t stream) {
  const float* x          = (const float*)d_in[0];
  const int*   eidx       = (const int*)d_in[1];
  const float* eattr      = (const float*)d_in[2];
  const int*   batch      = (const int*)d_in[3];
  const float* et_w       = (const float*)d_in[4];
  const float* et_b       = (const float*)d_in[5];
  const float* nn1_w1     = (const float*)d_in[6];
  const float* nn1_b1     = (const float*)d_in[7];
  const float* nn1_w2     = (const float*)d_in[8];
  const float* nn1_b2     = (const float*)d_in[9];
  const float* root_in    = (const float*)d_in[10];
  const float* bias_in    = (const float*)d_in[11];
  const float* convs_w1   = (const float*)d_in[12];
  const float* convs_b1   = (const float*)d_in[13];
  const float* convs_w2   = (const float*)d_in[14];
  const float* convs_b2   = (const float*)d_in[15];
  const float* convs_root = (const float*)d_in[16];
  const float* convs_bias = (const float*)d_in[17];
  const float* bn_gamma   = (const float*)d_in[18];
  const float* bn_beta    = (const float*)d_in[19];
  const float* lin1_w     = (const float*)d_in[20];
  const float* lin1_b     = (const float*)d_in[21];
  const float* lin2_w     = (const float*)d_in[22];
  const float* lin2_b     = (const float*)d_in[23];
  const float* lout_w     = (const float*)d_in[24];
  const float* lout_b     = (const float*)d_in[25];

  const int* srcp = eidx;
  const int* dstp = eidx + N_EDGES;

  float* ws     = (float*)d_ws;
  float* e_feat = ws;                        // E*64
  float* h1     = e_feat + N_EDGES * DIM;    // E*128
  float* agg    = h1 + N_EDGES * 128;        // N*64
  float* h_cur  = agg + N_NODES * DIM;       // N*64
  float* scale  = h_cur + N_NODES * DIM;     // 64
  float* shift  = scale + DIM;               // 64
  float* g      = shift + DIM;               // 64*64

  const int gNE = (N_EDGES * DIM + 255) / 256;    // 5000
  const int gH1 = (N_EDGES * 128 + 255) / 256;    // 10000
  const int gN  = (N_NODES * DIM + 255) / 256;    // 2500
  const int gMsg = (N_EDGES + 63) / 64;           // 313

  k_edge_feat<<<gNE, 256, 0, stream>>>(eattr, et_w, et_b, e_feat);

  // ---- layer 0 (in = 32) ----
  k_mlp1<<<gH1, 256, 0, stream>>>(e_feat, nn1_w1, nn1_b1, h1);
  k_root<NFEAT><<<gN, 256, 0, stream>>>(x, root_in, bias_in, agg);
  k_msg<NFEAT><<<gMsg, 256, 0, stream>>>(h1, x, srcp, dstp, nn1_w2, nn1_b2, agg);
  k_bnstats<<<DIM, 256, 0, stream>>>(agg, bn_gamma, bn_beta, scale, shift);
  k_bnapply<<<gN, 256, 0, stream>>>(agg, scale, shift, nullptr, h_cur);

  // ---- residual layers 1..4 (in = 64) ----
  for (int k = 0; k < 4; ++k) {
    k_mlp1<<<gH1, 256, 0, stream>>>(e_feat, convs_w1 + k * DIM * 128,
                                    convs_b1 + k * 128, h1);
    k_root<DIM><<<gN, 256, 0, stream>>>(h_cur, convs_root + k * DIM * DIM,
                                        convs_bias + k * DIM, agg);
    k_msg<DIM><<<gMsg, 256, 0, stream>>>(h1, h_cur, srcp, dstp,
                                         convs_w2 + k * 128 * DIM * DIM,
                                         convs_b2 + k * DIM * DIM, agg);
    k_bnstats<<<DIM, 256, 0, stream>>>(agg, bn_gamma + (k + 1) * DIM,
                                       bn_beta + (k + 1) * DIM, scale, shift);
    k_bnapply<<<gN, 256, 0, stream>>>(agg, scale, shift, h_cur, h_cur);
  }

  hipMemsetAsync(g, 0, N_GRAPHS * DIM * sizeof(float), stream);
  k_pool<<<gN, 256, 0, stream>>>(h_cur, batch, g);
  k_head<<<1, 256, 0, stream>>>(g, lin1_w, lin1_b, lin2_w, lin2_b,
                                lout_w, lout_b, (float*)d_out);
}

// Round 2
// 679.804 us; speedup vs baseline: 3.8286x; 3.8286x over previous
//
#include <hip/hip_runtime.h>
#include <hip/hip_bf16.h>
#include <math.h>

#define N_NODES 10000
#define N_EDGES 20000
#define N_GRAPHS 64
#define DIM 64
#define NFEAT 32
#define EDIM 16
#define NCLS 10

typedef short short8 __attribute__((ext_vector_type(8)));
typedef float f32x16 __attribute__((ext_vector_type(16)));

static __device__ __forceinline__ short f2b(float f) {
  __hip_bfloat16 h = __float2bfloat16(f);
  return __builtin_bit_cast(short, h);
}

// e = edge_attr @ et_w + et_b : [E,16]@[16,64]
__global__ __launch_bounds__(256) void k_edge_feat(const float* __restrict__ ea,
    const float* __restrict__ w, const float* __restrict__ b,
    float* __restrict__ out) {
  int idx = blockIdx.x * 256 + threadIdx.x;
  if (idx >= N_EDGES * DIM) return;
  int e = idx >> 6, o = idx & 63;
  float a = b[o];
  const float* er = ea + e * EDIM;
  #pragma unroll
  for (int i = 0; i < EDIM; ++i) a = fmaf(er[i], w[i * DIM + o], a);
  out[idx] = a;
}

// h1 = relu(e @ w1 + b1) : [E,64]@[64,128]
__global__ __launch_bounds__(256) void k_mlp1(const float* __restrict__ ef,
    const float* __restrict__ w1, const float* __restrict__ b1,
    float* __restrict__ h1) {
  int idx = blockIdx.x * 256 + threadIdx.x;
  if (idx >= N_EDGES * 128) return;
  int e = idx >> 7, j = idx & 127;
  float a = b1[j];
  const float* er = ef + e * DIM;
  #pragma unroll 8
  for (int i = 0; i < DIM; ++i) a = fmaf(er[i], w1[i * 128 + j], a);
  h1[idx] = fmaxf(a, 0.f);
}

// agg = h @ root + bias (initializes agg before edge scatter)
template<int IN>
__global__ __launch_bounds__(256) void k_root(const float* __restrict__ h,
    const float* __restrict__ root, const float* __restrict__ bias,
    float* __restrict__ agg) {
  int idx = blockIdx.x * 256 + threadIdx.x;
  if (idx >= N_NODES * DIM) return;
  int n = idx >> 6, o = idx & 63;
  float a = bias[o];
  const float* hr = h + n * IN;
  #pragma unroll 8
  for (int i = 0; i < IN; ++i) a = fmaf(hr[i], root[i * DIM + o], a);
  agg[idx] = a;
}

// Pack w2 [K,64] f32 (+ b2 [IN,64] appended as K..K+IN-1) into fragment-ordered
// bf16: short8 index p = (S*2+n)*64 + lane holds B[S*16 + (lane>>5)*8 + e][n*32 + (lane&31)].
// The (lane>>5)*8+e k-slot guess only needs to MATCH the A-side generation (it does).
__global__ __launch_bounds__(256) void k_pack(const float* __restrict__ w2,
    const float* __restrict__ b2, int K, int total8, short* __restrict__ out) {
  int p = blockIdx.x * 256 + threadIdx.x;
  if (p >= total8) return;
  int l = p & 63;
  int n = (p >> 6) & 1;
  int S = p >> 7;
  int col = n * 32 + (l & 31);
  int kb = S * 16 + ((l >> 5) << 3);
  short8 v;
  #pragma unroll
  for (int u = 0; u < 8; ++u) {
    int k = kb + u;
    float f = (k < K) ? w2[(size_t)k * 64 + col] : b2[(size_t)(k - K) * 64 + col];
    v[u] = f2b(f);
  }
  ((short8*)out)[p] = v;
}

// Implicit-A MFMA GEMM: msg[e,o] = sum_k A[e,k]*B[k,o], A[e,j*IN+i]=h1[e,j]*x[src[e],i].
// Block = 128 edges (4 waves x 32), full N=64 (2 n-tiles of 32x32x16 mfma).
// grid.y splits K into CHUNK-sized pieces; partial sums atomicAdd into agg.
// Bias rows (A=x, B=b2) run only on blockIdx.y==0.
template<int IN, int CHUNK>
__global__ __launch_bounds__(256) void k_msg_mfma(
    const float* __restrict__ h1, const float* __restrict__ xin,
    const int* __restrict__ src, const int* __restrict__ dst,
    const short* __restrict__ pk, float* __restrict__ agg) {
  constexpr int QN = IN / 16;     // mfma steps sharing one j
  constexpr int JR = CHUNK / IN;  // j values per chunk (=32)
  constexpr int K  = 128 * IN;
  __shared__ float sh[128][JR + 1];
  const int t = threadIdx.x;
  const int l = t & 63;
  const int w = t >> 6;
  const int le = l & 31;
  const int h8 = (l >> 5) << 3;
  const int e0 = blockIdx.x * 128;
  const int jbase = blockIdx.y * JR;

  // stage h1[e0..e0+127][jbase..jbase+31] -> LDS (padded stride 33: conflict-free)
  {
    int row = t >> 1, half = t & 1;
    int e = e0 + row;
    const float* sp = h1 + (size_t)(e < N_EDGES ? e : 0) * 128 + jbase + half * 16;
    float4 v0 = ((const float4*)sp)[0];
    float4 v1 = ((const float4*)sp)[1];
    float4 v2 = ((const float4*)sp)[2];
    float4 v3 = ((const float4*)sp)[3];
    if (e >= N_EDGES) { v0 = v1 = v2 = v3 = float4{0.f, 0.f, 0.f, 0.f}; }
    float* dr = &sh[row][half * 16];
    dr[0]=v0.x; dr[1]=v0.y; dr[2]=v0.z; dr[3]=v0.w;
    dr[4]=v1.x; dr[5]=v1.y; dr[6]=v1.z; dr[7]=v1.w;
    dr[8]=v2.x; dr[9]=v2.y; dr[10]=v2.z; dr[11]=v2.w;
    dr[12]=v3.x; dr[13]=v3.y; dr[14]=v3.z; dr[15]=v3.w;
  }

  // x fragment registers: xr[q][u] = x[src[e]][q*16 + h8 + u] (whole K-loop reuse)
  const int eme = e0 + w * 32 + le;
  const int srow = src[eme < N_EDGES ? eme : 0];
  const float* xp = xin + (size_t)srow * IN + h8;
  float xr[QN][8];
  #pragma unroll
  for (int q = 0; q < QN; ++q) {
    float4 a = *(const float4*)(xp + q * 16);
    float4 b = *(const float4*)(xp + q * 16 + 4);
    xr[q][0]=a.x; xr[q][1]=a.y; xr[q][2]=a.z; xr[q][3]=a.w;
    xr[q][4]=b.x; xr[q][5]=b.y; xr[q][6]=b.z; xr[q][7]=b.w;
  }

  f32x16 acc0 = {}; f32x16 acc1 = {};
  const short8* B = (const short8*)pk;
  __syncthreads();

  const int hrow = w * 32 + le;
  #pragma unroll 4
  for (int jj = 0; jj < JR; ++jj) {
    float hv = sh[hrow][jj];
    #pragma unroll
    for (int q = 0; q < QN; ++q) {
      int S = (jbase + jj) * QN + q;
      short8 b0 = B[S * 128 + l];
      short8 b1 = B[S * 128 + 64 + l];
      short8 av;
      #pragma unroll
      for (int u = 0; u < 8; ++u) av[u] = f2b(hv * xr[q][u]);
      acc0 = __builtin_amdgcn_mfma_f32_32x32x16_bf16(av, b0, acc0, 0, 0, 0);
      acc1 = __builtin_amdgcn_mfma_f32_32x32x16_bf16(av, b1, acc1, 0, 0, 0);
    }
  }

  if (blockIdx.y == 0) {  // bias rows: A = x directly
    #pragma unroll
    for (int q = 0; q < QN; ++q) {
      int S = K / 16 + q;
      short8 b0 = B[S * 128 + l];
      short8 b1 = B[S * 128 + 64 + l];
      short8 av;
      #pragma unroll
      for (int u = 0; u < 8; ++u) av[u] = f2b(xr[q][u]);
      acc0 = __builtin_amdgcn_mfma_f32_32x32x16_bf16(av, b0, acc0, 0, 0, 0);
      acc1 = __builtin_amdgcn_mfma_f32_32x32x16_bf16(av, b1, acc1, 0, 0, 0);
    }
  }

  // C/D layout (verified m74/m101): col = lane&31, row = (reg&3)+8*(reg>>2)+4*(lane>>5)
  #pragma unroll
  for (int v = 0; v < 16; ++v) {
    int r = (v & 3) + ((v >> 2) << 3) + ((l >> 5) << 2);
    int e2 = e0 + w * 32 + r;
    if (e2 < N_EDGES) {
      float* ap = agg + (size_t)dst[e2] * 64 + le;
      atomicAdd(ap, acc0[v]);
      atomicAdd(ap + 32, acc1[v]);
    }
  }
}

// BatchNorm stats (biased var) per channel -> scale/shift. f64 accumulation.
__global__ __launch_bounds__(256) void k_bnstats(const float* __restrict__ agg,
    const float* __restrict__ gamma, const float* __restrict__ beta,
    float* __restrict__ scale, float* __restrict__ shift) {
  int c = blockIdx.x;
  int t = threadIdx.x;
  double s = 0.0, s2 = 0.0;
  for (int n = t; n < N_NODES; n += 256) {
    float v = agg[n * DIM + c];
    s += v;
    s2 += (double)v * v;
  }
  __shared__ double sh0[256];
  __shared__ double sh1[256];
  sh0[t] = s; sh1[t] = s2;
  __syncthreads();
  for (int w = 128; w > 0; w >>= 1) {
    if (t < w) { sh0[t] += sh0[t + w]; sh1[t] += sh1[t + w]; }
    __syncthreads();
  }
  if (t == 0) {
    double m = sh0[0] / N_NODES;
    double v = sh1[0] / N_NODES - m * m;
    float inv = (float)(1.0 / sqrt(v + 1e-5));
    float sc = gamma[c] * inv;
    scale[c] = sc;
    shift[c] = beta[c] - (float)m * sc;
  }
}

// h_out = relu(agg*scale+shift) [+ resid]
__global__ __launch_bounds__(256) void k_bnapply(const float* __restrict__ agg,
    const float* __restrict__ scale, const float* __restrict__ shift,
    const float* __restrict__ resid, float* __restrict__ hout) {
  int idx = blockIdx.x * 256 + threadIdx.x;
  if (idx >= N_NODES * DIM) return;
  int c = idx & 63;
  float v = fmaxf(fmaf(agg[idx], scale[c], shift[c]), 0.f);
  if (resid) v += resid[idx];
  hout[idx] = v;
}

// global_max_pool: h >= 0 so uint-bits atomicMax is order-correct (init 0)
__global__ __launch_bounds__(256) void k_pool(const float* __restrict__ h,
    const int* __restrict__ batch, float* __restrict__ g) {
  int idx = blockIdx.x * 256 + threadIdx.x;
  if (idx >= N_NODES * DIM) return;
  int n = idx >> 6, c = idx & 63;
  atomicMax((unsigned int*)&g[batch[n] * DIM + c], __float_as_uint(h[idx]));
}

// head: relu(g@w1+b1) -> relu(@w2+b2) -> sigmoid(@wo+bo). One block.
__global__ __launch_bounds__(256) void k_head(const float* __restrict__ g,
    const float* __restrict__ w1, const float* __restrict__ b1,
    const float* __restrict__ w2, const float* __restrict__ b2,
    const float* __restrict__ wo, const float* __restrict__ bo,
    float* __restrict__ out) {
  __shared__ float s0[N_GRAPHS * DIM];
  __shared__ float s1[N_GRAPHS * DIM];
  int t = threadIdx.x;
  for (int idx = t; idx < N_GRAPHS * DIM; idx += 256) s0[idx] = g[idx];
  __syncthreads();
  for (int idx = t; idx < N_GRAPHS * DIM; idx += 256) {
    int r = idx >> 6, c = idx & 63;
    float a = b1[c];
    #pragma unroll 8
    for (int i = 0; i < DIM; ++i) a = fmaf(s0[(r << 6) + i], w1[i * DIM + c], a);
    s1[idx] = fmaxf(a, 0.f);
  }
  __syncthreads();
  for (int idx = t; idx < N_GRAPHS * DIM; idx += 256) {
    int r = idx >> 6, c = idx & 63;
    float a = b2[c];
    #pragma unroll 8
    for (int i = 0; i < DIM; ++i) a = fmaf(s1[(r << 6) + i], w2[i * DIM + c], a);
    s0[idx] = fmaxf(a, 0.f);
  }
  __syncthreads();
  for (int idx = t; idx < N_GRAPHS * NCLS; idx += 256) {
    int r = idx / NCLS, c = idx % NCLS;
    float a = bo[c];
    #pragma unroll 8
    for (int i = 0; i < DIM; ++i) a = fmaf(s0[(r << 6) + i], wo[i * NCLS + c], a);
    out[idx] = 1.f / (1.f + expf(-a));
  }
}

extern "C" void kernel_launch(void* const* d_in, const int* in_sizes, int n_in,
                              void* d_out, int out_size, void* d_ws, size_t ws_size,
                              hipStream_t stream) {
  const float* x          = (const float*)d_in[0];
  const int*   eidx       = (const int*)d_in[1];
  const float* eattr      = (const float*)d_in[2];
  const int*   batch      = (const int*)d_in[3];
  const float* et_w       = (const float*)d_in[4];
  const float* et_b       = (const float*)d_in[5];
  const float* nn1_w1     = (const float*)d_in[6];
  const float* nn1_b1     = (const float*)d_in[7];
  const float* nn1_w2     = (const float*)d_in[8];
  const float* nn1_b2     = (const float*)d_in[9];
  const float* root_in    = (const float*)d_in[10];
  const float* bias_in    = (const float*)d_in[11];
  const float* convs_w1   = (const float*)d_in[12];
  const float* convs_b1   = (const float*)d_in[13];
  const float* convs_w2   = (const float*)d_in[14];
  const float* convs_b2   = (const float*)d_in[15];
  const float* convs_root = (const float*)d_in[16];
  const float* convs_bias = (const float*)d_in[17];
  const float* bn_gamma   = (const float*)d_in[18];
  const float* bn_beta    = (const float*)d_in[19];
  const float* lin1_w     = (const float*)d_in[20];
  const float* lin1_b     = (const float*)d_in[21];
  const float* lin2_w     = (const float*)d_in[22];
  const float* lin2_b     = (const float*)d_in[23];
  const float* lout_w     = (const float*)d_in[24];
  const float* lout_b     = (const float*)d_in[25];

  const int* srcp = eidx;
  const int* dstp = eidx + N_EDGES;

  float* ws     = (float*)d_ws;
  float* e_feat = ws;                        // E*64
  float* h1     = e_feat + N_EDGES * DIM;    // E*128
  float* agg    = h1 + N_EDGES * 128;        // N*64
  float* h_cur  = agg + N_NODES * DIM;       // N*64
  float* scale  = h_cur + N_NODES * DIM;     // 64
  float* shift  = scale + DIM;               // 64
  float* g      = shift + DIM;               // 64*64
  // packed bf16 W2(+bias rows), 16B-aligned
  short* pk0 = (short*)(g + N_GRAPHS * DIM);                // (4096+32)*64 = 264192 shorts
  const int PK0 = (4096 + NFEAT) / 16 * 128;                // short8 count = 33024
  const int PKL = (8192 + DIM) / 16 * 128;                  // short8 count = 66048
  short* pkL[4];
  for (int k = 0; k < 4; ++k) pkL[k] = pk0 + 8 * (PK0 + k * PKL);

  const int gNE = (N_EDGES * DIM + 255) / 256;
  const int gH1 = (N_EDGES * 128 + 255) / 256;
  const int gN  = (N_NODES * DIM + 255) / 256;
  const int gMsg = (N_EDGES + 127) / 128;                   // 157

  // pack all layers' W2 up front
  k_pack<<<(PK0 + 255) / 256, 256, 0, stream>>>(nn1_w2, nn1_b2, 4096, PK0, pk0);
  for (int k = 0; k < 4; ++k)
    k_pack<<<(PKL + 255) / 256, 256, 0, stream>>>(convs_w2 + (size_t)k * 8192 * 64,
                                                  convs_b2 + k * DIM * 64, 8192, PKL, pkL[k]);

  k_edge_feat<<<gNE, 256, 0, stream>>>(eattr, et_w, et_b, e_feat);

  // ---- layer 0 (in = 32, K = 4096, 4 chunks of 1024) ----
  k_mlp1<<<gH1, 256, 0, stream>>>(e_feat, nn1_w1, nn1_b1, h1);
  k_root<NFEAT><<<gN, 256, 0, stream>>>(x, root_in, bias_in, agg);
  k_msg_mfma<NFEAT, 1024><<<dim3(gMsg, 4), 256, 0, stream>>>(h1, x, srcp, dstp, pk0, agg);
  k_bnstats<<<DIM, 256, 0, stream>>>(agg, bn_gamma, bn_beta, scale, shift);
  k_bnapply<<<gN, 256, 0, stream>>>(agg, scale, shift, nullptr, h_cur);

  // ---- residual layers 1..4 (in = 64, K = 8192, 4 chunks of 2048) ----
  for (int k = 0; k < 4; ++k) {
    k_mlp1<<<gH1, 256, 0, stream>>>(e_feat, convs_w1 + k * DIM * 128,
                                    convs_b1 + k * 128, h1);
    k_root<DIM><<<gN, 256, 0, stream>>>(h_cur, convs_root + k * DIM * DIM,
                                        convs_bias + k * DIM, agg);
    k_msg_mfma<DIM, 2048><<<dim3(gMsg, 4), 256, 0, stream>>>(h1, h_cur, srcp, dstp,
                                                             pkL[k], agg);
    k_bnstats<<<DIM, 256, 0, stream>>>(agg, bn_gamma + (k + 1) * DIM,
                                       bn_beta + (k + 1) * DIM, scale, shift);
    k_bnapply<<<gN, 256, 0, stream>>>(agg, scale, shift, h_cur, h_cur);
  }

  hipMemsetAsync(g, 0, N_GRAPHS * DIM * sizeof(float), stream);
  k_pool<<<gN, 256, 0, stream>>>(h_cur, batch, g);
  k_head<<<1, 256, 0, stream>>>(g, lin1_w, lin1_b, lin2_w, lin2_b,
                                lout_w, lout_b, (float*)d_out);
}

// Round 3
// 660.917 us; speedup vs baseline: 3.9380x; 1.0286x over previous
//
#include <hip/hip_runtime.h>
#include <hip/hip_bf16.h>
#include <math.h>

#define N_NODES 10000
#define N_EDGES 20000
#define N_GRAPHS 64
#define DIM 64
#define NFEAT 32
#define EDIM 16
#define NCLS 10

typedef short short8 __attribute__((ext_vector_type(8)));
typedef float f32x4 __attribute__((ext_vector_type(4)));

static __device__ __forceinline__ short f2b(float f) {
  __hip_bfloat16 h = __float2bfloat16(f);
  return __builtin_bit_cast(short, h);
}

// e = edge_attr @ et_w + et_b : [E,16]@[16,64]
__global__ __launch_bounds__(256) void k_edge_feat(const float* __restrict__ ea,
    const float* __restrict__ w, const float* __restrict__ b,
    float* __restrict__ out) {
  int idx = blockIdx.x * 256 + threadIdx.x;
  if (idx >= N_EDGES * DIM) return;
  int e = idx >> 6, o = idx & 63;
  float a = b[o];
  const float* er = ea + e * EDIM;
  #pragma unroll
  for (int i = 0; i < EDIM; ++i) a = fmaf(er[i], w[i * DIM + o], a);
  out[idx] = a;
}

// h1 = relu(e @ w1 + b1) : [E,64]@[64,128]
__global__ __launch_bounds__(256) void k_mlp1(const float* __restrict__ ef,
    const float* __restrict__ w1, const float* __restrict__ b1,
    float* __restrict__ h1) {
  int idx = blockIdx.x * 256 + threadIdx.x;
  if (idx >= N_EDGES * 128) return;
  int e = idx >> 7, j = idx & 127;
  float a = b1[j];
  const float* er = ef + e * DIM;
  #pragma unroll 8
  for (int i = 0; i < DIM; ++i) a = fmaf(er[i], w1[i * 128 + j], a);
  h1[idx] = fmaxf(a, 0.f);
}

// agg = h @ root + bias; block 0 also zeroes the BN partial-sum buffer.
template<int IN>
__global__ __launch_bounds__(256) void k_root(const float* __restrict__ h,
    const float* __restrict__ root, const float* __restrict__ bias,
    float* __restrict__ agg, double* __restrict__ part) {
  if (blockIdx.x == 0 && threadIdx.x < 128) part[threadIdx.x] = 0.0;
  int idx = blockIdx.x * 256 + threadIdx.x;
  if (idx >= N_NODES * DIM) return;
  int n = idx >> 6, o = idx & 63;
  float a = bias[o];
  const float* hr = h + n * IN;
  #pragma unroll 8
  for (int i = 0; i < IN; ++i) a = fmaf(hr[i], root[i * DIM + o], a);
  agg[idx] = a;
}

// Transpose-pack w2 [K,64] f32 (+ b2 [IN,64] as rows K..K+IN-1) into
// fragment-ordered bf16 for 16x16x32 MFMA B-operands:
// short8 p = (S*4+n)*64 + l holds B[S*32 + (l>>4)*8 + u][n*16 + (l&15)].
// One block per S (32 k-rows x 64 cols), LDS-staged: coalesced in and out.
__global__ __launch_bounds__(256) void k_pack(const float* __restrict__ w2,
    const float* __restrict__ b2, int K, short* __restrict__ out) {
  __shared__ float tile[32][65];
  const int S = blockIdx.x;
  const int t = threadIdx.x;
  #pragma unroll
  for (int it = 0; it < 2; ++it) {
    int idx = t + it * 256;          // float4 index in [0,512)
    int r = idx >> 4, c4 = idx & 15;
    int k = S * 32 + r;
    const float* sp = (k < K) ? (w2 + (size_t)k * 64 + c4 * 4)
                              : (b2 + (size_t)(k - K) * 64 + c4 * 4);
    float4 v = *(const float4*)sp;
    float* dr = &tile[r][c4 * 4];
    dr[0] = v.x; dr[1] = v.y; dr[2] = v.z; dr[3] = v.w;
  }
  __syncthreads();
  const int n = t >> 6, l = t & 63;
  const int klo = (l >> 4) << 3;
  const int col = n * 16 + (l & 15);
  short8 o;
  #pragma unroll
  for (int u = 0; u < 8; ++u) o[u] = f2b(tile[klo + u][col]);
  ((short8*)out)[S * 256 + t] = o;
}

// Implicit-A MFMA GEMM (16x16x32): msg[e,o] = sum_k A[e,k]*B[k,o],
// A[e, j*IN+i] = h1[e,j] * x[src[e],i]. Wave = 16 edges, 4 n-tiles of 16.
// Block = 4 waves = 64 edges; grid.y = 4 K-chunks -> atomicAdd into agg.
template<int IN, int CHUNK>
__global__ __launch_bounds__(256) void k_msg16(
    const float* __restrict__ h1, const float* __restrict__ xin,
    const int* __restrict__ src, const int* __restrict__ dst,
    const short* __restrict__ pk, float* __restrict__ agg) {
  constexpr int QN = IN / 32;            // K=32 windows per j
  constexpr int JR = CHUNK / IN;         // j's per chunk (=32)
  constexpr int KS = (128 * IN) / 32;    // bias S base
  __shared__ float sh[64][JR + 1];
  const int t = threadIdx.x;
  const int l = t & 63;
  const int w = t >> 6;
  const int e0 = blockIdx.x * 64;
  const int jbase = blockIdx.y * JR;

  // stage h1[e0..e0+63][jbase..jbase+31] (pad 33: conflict-free)
  #pragma unroll
  for (int it = 0; it < 2; ++it) {
    int idx = t + it * 256;
    int row = idx >> 3, c4 = idx & 7;
    int e = e0 + row;
    float4 v = {0.f, 0.f, 0.f, 0.f};
    if (e < N_EDGES) v = *(const float4*)(h1 + (size_t)e * 128 + jbase + c4 * 4);
    float* dr = &sh[row][c4 * 4];
    dr[0] = v.x; dr[1] = v.y; dr[2] = v.z; dr[3] = v.w;
  }

  // x fragments (live whole K-loop): xr[q][u] = x[src[e]][q*32 + (l>>4)*8 + u]
  const int eme = e0 + w * 16 + (l & 15);
  const int srow = src[eme < N_EDGES ? eme : 0];
  const int i8 = (l >> 4) << 3;
  float xr[QN][8];
  #pragma unroll
  for (int q = 0; q < QN; ++q) {
    const float* xp = xin + (size_t)srow * IN + q * 32 + i8;
    float4 a = *(const float4*)xp;
    float4 b = *(const float4*)(xp + 4);
    xr[q][0] = a.x; xr[q][1] = a.y; xr[q][2] = a.z; xr[q][3] = a.w;
    xr[q][4] = b.x; xr[q][5] = b.y; xr[q][6] = b.z; xr[q][7] = b.w;
  }

  f32x4 acc0 = {}, acc1 = {}, acc2 = {}, acc3 = {};
  const short8* B = (const short8*)pk;
  __syncthreads();

  const int hrow = w * 16 + (l & 15);
  #pragma unroll 2
  for (int jj = 0; jj < JR; ++jj) {
    float hv = sh[hrow][jj];
    #pragma unroll
    for (int q = 0; q < QN; ++q) {
      int S = (jbase + jj) * QN + q;
      const short8* bp = B + ((size_t)S << 8) + l;
      short8 b0 = bp[0], b1 = bp[64], b2 = bp[128], b3 = bp[192];
      short8 av;
      #pragma unroll
      for (int u = 0; u < 8; ++u) av[u] = f2b(hv * xr[q][u]);
      acc0 = __builtin_amdgcn_mfma_f32_16x16x32_bf16(av, b0, acc0, 0, 0, 0);
      acc1 = __builtin_amdgcn_mfma_f32_16x16x32_bf16(av, b1, acc1, 0, 0, 0);
      acc2 = __builtin_amdgcn_mfma_f32_16x16x32_bf16(av, b2, acc2, 0, 0, 0);
      acc3 = __builtin_amdgcn_mfma_f32_16x16x32_bf16(av, b3, acc3, 0, 0, 0);
    }
  }

  if (blockIdx.y == 0) {  // bias rows: A = x directly
    #pragma unroll
    for (int q = 0; q < QN; ++q) {
      int S = KS + q;
      const short8* bp = B + ((size_t)S << 8) + l;
      short8 b0 = bp[0], b1 = bp[64], b2 = bp[128], b3 = bp[192];
      short8 av;
      #pragma unroll
      for (int u = 0; u < 8; ++u) av[u] = f2b(xr[q][u]);
      acc0 = __builtin_amdgcn_mfma_f32_16x16x32_bf16(av, b0, acc0, 0, 0, 0);
      acc1 = __builtin_amdgcn_mfma_f32_16x16x32_bf16(av, b1, acc1, 0, 0, 0);
      acc2 = __builtin_amdgcn_mfma_f32_16x16x32_bf16(av, b2, acc2, 0, 0, 0);
      acc3 = __builtin_amdgcn_mfma_f32_16x16x32_bf16(av, b3, acc3, 0, 0, 0);
    }
  }

  // C/D (m89/m91): col = lane&15, row = (lane>>4)*4 + reg
  #pragma unroll
  for (int v = 0; v < 4; ++v) {
    int e2 = e0 + w * 16 + ((l >> 4) << 2) + v;
    if (e2 < N_EDGES) {
      float* ap = agg + (size_t)dst[e2] * 64 + (l & 15);
      atomicAdd(ap +  0, acc0[v]);
      atomicAdd(ap + 16, acc1[v]);
      atomicAdd(ap + 32, acc2[v]);
      atomicAdd(ap + 48, acc3[v]);
    }
  }
}

// BN partial sums: coalesced, f64 local accum, f64 global atomics.
// part[0..63] = sum, part[64..127] = sumsq. grid = 200 blocks x 50 rows.
__global__ __launch_bounds__(256) void k_bnpart(const float* __restrict__ agg,
    double* __restrict__ part) {
  const int t = threadIdx.x;
  const int c = t & 63, rg = t >> 6;
  const int r0 = blockIdx.x * 50;
  const int r1 = min(r0 + 50, N_NODES);
  double s = 0.0, s2 = 0.0;
  for (int r = r0 + rg; r < r1; r += 4) {
    float v = agg[(size_t)r * 64 + c];
    s += v;
    s2 += (double)v * v;
  }
  __shared__ double shs[4][64];
  __shared__ double shq[4][64];
  shs[rg][c] = s; shq[rg][c] = s2;
  __syncthreads();
  if (t < 64) {
    double ts = shs[0][t] + shs[1][t] + shs[2][t] + shs[3][t];
    double tq = shq[0][t] + shq[1][t] + shq[2][t] + shq[3][t];
    atomicAdd(&part[t], ts);
    atomicAdd(&part[64 + t], tq);
  }
}

// h_out = relu(agg*scale+shift) [+ resid]; finalize folded in (reads part).
__global__ __launch_bounds__(256) void k_bnapply(const float* __restrict__ agg,
    const double* __restrict__ part, const float* __restrict__ gamma,
    const float* __restrict__ beta, const float* __restrict__ resid,
    float* __restrict__ hout) {
  int idx = blockIdx.x * 256 + threadIdx.x;
  if (idx >= N_NODES * DIM) return;
  int c = idx & 63;
  float m = (float)(part[c] * (1.0 / N_NODES));
  float s2 = (float)(part[64 + c] * (1.0 / N_NODES));
  float inv = 1.0f / sqrtf(s2 - m * m + 1e-5f);
  float sc = gamma[c] * inv;
  float sf = beta[c] - m * sc;
  float v = fmaxf(fmaf(agg[idx], sc, sf), 0.f);
  if (resid) v += resid[idx];
  hout[idx] = v;
}

// global_max_pool: h >= 0 so uint-bits atomicMax is order-correct (init 0)
__global__ __launch_bounds__(256) void k_pool(const float* __restrict__ h,
    const int* __restrict__ batch, float* __restrict__ g) {
  int idx = blockIdx.x * 256 + threadIdx.x;
  if (idx >= N_NODES * DIM) return;
  int n = idx >> 6, c = idx & 63;
  atomicMax((unsigned int*)&g[batch[n] * DIM + c], __float_as_uint(h[idx]));
}

// head: relu(g@w1+b1) -> relu(@w2+b2) -> sigmoid(@wo+bo). One block.
__global__ __launch_bounds__(256) void k_head(const float* __restrict__ g,
    const float* __restrict__ w1, const float* __restrict__ b1,
    const float* __restrict__ w2, const float* __restrict__ b2,
    const float* __restrict__ wo, const float* __restrict__ bo,
    float* __restrict__ out) {
  __shared__ float s0[N_GRAPHS * DIM];
  __shared__ float s1[N_GRAPHS * DIM];
  int t = threadIdx.x;
  for (int idx = t; idx < N_GRAPHS * DIM; idx += 256) s0[idx] = g[idx];
  __syncthreads();
  for (int idx = t; idx < N_GRAPHS * DIM; idx += 256) {
    int r = idx >> 6, c = idx & 63;
    float a = b1[c];
    #pragma unroll 8
    for (int i = 0; i < DIM; ++i) a = fmaf(s0[(r << 6) + i], w1[i * DIM + c], a);
    s1[idx] = fmaxf(a, 0.f);
  }
  __syncthreads();
  for (int idx = t; idx < N_GRAPHS * DIM; idx += 256) {
    int r = idx >> 6, c = idx & 63;
    float a = b2[c];
    #pragma unroll 8
    for (int i = 0; i < DIM; ++i) a = fmaf(s1[(r << 6) + i], w2[i * DIM + c], a);
    s0[idx] = fmaxf(a, 0.f);
  }
  __syncthreads();
  for (int idx = t; idx < N_GRAPHS * NCLS; idx += 256) {
    int r = idx / NCLS, c = idx % NCLS;
    float a = bo[c];
    #pragma unroll 8
    for (int i = 0; i < DIM; ++i) a = fmaf(s0[(r << 6) + i], wo[i * NCLS + c], a);
    out[idx] = 1.f / (1.f + expf(-a));
  }
}

extern "C" void kernel_launch(void* const* d_in, const int* in_sizes, int n_in,
                              void* d_out, int out_size, void* d_ws, size_t ws_size,
                              hipStream_t stream) {
  const float* x          = (const float*)d_in[0];
  const int*   eidx       = (const int*)d_in[1];
  const float* eattr      = (const float*)d_in[2];
  const int*   batch      = (const int*)d_in[3];
  const float* et_w       = (const float*)d_in[4];
  const float* et_b       = (const float*)d_in[5];
  const float* nn1_w1     = (const float*)d_in[6];
  const float* nn1_b1     = (const float*)d_in[7];
  const float* nn1_w2     = (const float*)d_in[8];
  const float* nn1_b2     = (const float*)d_in[9];
  const float* root_in    = (const float*)d_in[10];
  const float* bias_in    = (const float*)d_in[11];
  const float* convs_w1   = (const float*)d_in[12];
  const float* convs_b1   = (const float*)d_in[13];
  const float* convs_w2   = (const float*)d_in[14];
  const float* convs_b2   = (const float*)d_in[15];
  const float* convs_root = (const float*)d_in[16];
  const float* convs_bias = (const float*)d_in[17];
  const float* bn_gamma   = (const float*)d_in[18];
  const float* bn_beta    = (const float*)d_in[19];
  const float* lin1_w     = (const float*)d_in[20];
  const float* lin1_b     = (const float*)d_in[21];
  const float* lin2_w     = (const float*)d_in[22];
  const float* lin2_b     = (const float*)d_in[23];
  const float* lout_w     = (const float*)d_in[24];
  const float* lout_b     = (const float*)d_in[25];

  const int* srcp = eidx;
  const int* dstp = eidx + N_EDGES;

  double* part  = (double*)d_ws;                       // 128 doubles (1KB)
  float* e_feat = (float*)(part + 128);                // E*64
  float* h1     = e_feat + N_EDGES * DIM;              // E*128
  float* agg    = h1 + N_EDGES * 128;                  // N*64
  float* h_cur  = agg + N_NODES * DIM;                 // N*64
  float* g      = h_cur + N_NODES * DIM;               // 64*64
  short* pk0    = (short*)(g + N_GRAPHS * DIM);        // packed bf16 B
  const int S0 = (4096 + NFEAT) / 32;                  // 129 S-blocks (layer 0)
  const int SL = (8192 + DIM) / 32;                    // 258 S-blocks (layers)
  short* pkL[4];
  for (int k = 0; k < 4; ++k) pkL[k] = pk0 + 2048 * (S0 + k * SL);

  const int gNE = (N_EDGES * DIM + 255) / 256;
  const int gH1 = (N_EDGES * 128 + 255) / 256;
  const int gN  = (N_NODES * DIM + 255) / 256;
  const int gMsg = (N_EDGES + 63) / 64;                // 313

  // pack all layers' W2 up front (coalesced transpose-pack)
  k_pack<<<S0, 256, 0, stream>>>(nn1_w2, nn1_b2, 4096, pk0);
  for (int k = 0; k < 4; ++k)
    k_pack<<<SL, 256, 0, stream>>>(convs_w2 + (size_t)k * 8192 * 64,
                                   convs_b2 + k * DIM * 64, 8192, pkL[k]);

  k_edge_feat<<<gNE, 256, 0, stream>>>(eattr, et_w, et_b, e_feat);

  // ---- layer 0 (IN = 32, K = 4096, 4 chunks of 1024) ----
  k_mlp1<<<gH1, 256, 0, stream>>>(e_feat, nn1_w1, nn1_b1, h1);
  k_root<NFEAT><<<gN, 256, 0, stream>>>(x, root_in, bias_in, agg, part);
  k_msg16<NFEAT, 1024><<<dim3(gMsg, 4), 256, 0, stream>>>(h1, x, srcp, dstp, pk0, agg);
  k_bnpart<<<200, 256, 0, stream>>>(agg, part);
  k_bnapply<<<gN, 256, 0, stream>>>(agg, part, bn_gamma, bn_beta, nullptr, h_cur);

  // ---- residual layers 1..4 (IN = 64, K = 8192, 4 chunks of 2048) ----
  for (int k = 0; k < 4; ++k) {
    k_mlp1<<<gH1, 256, 0, stream>>>(e_feat, convs_w1 + k * DIM * 128,
                                    convs_b1 + k * 128, h1);
    k_root<DIM><<<gN, 256, 0, stream>>>(h_cur, convs_root + k * DIM * DIM,
                                        convs_bias + k * DIM, agg, part);
    k_msg16<DIM, 2048><<<dim3(gMsg, 4), 256, 0, stream>>>(h1, h_cur, srcp, dstp,
                                                          pkL[k], agg);
    k_bnpart<<<200, 256, 0, stream>>>(agg, part);
    k_bnapply<<<gN, 256, 0, stream>>>(agg, part, bn_gamma + (k + 1) * DIM,
                                      bn_beta + (k + 1) * DIM, h_cur, h_cur);
  }

  hipMemsetAsync(g, 0, N_GRAPHS * DIM * sizeof(float), stream);
  k_pool<<<gN, 256, 0, stream>>>(h_cur, batch, g);
  k_head<<<1, 256, 0, stream>>>(g, lin1_w, lin1_b, lin2_w, lin2_b,
                                lout_w, lout_b, (float*)d_out);
}

// Round 5
// 589.940 us; speedup vs baseline: 4.4118x; 1.1203x over previous
//
#include <hip/hip_runtime.h>
#include <hip/hip_bf16.h>
#include <math.h>

#define N_NODES 10000
#define N_EDGES 20000
#define N_GRAPHS 64
#define DIM 64
#define NFEAT 32
#define EDIM 16
#define NCLS 10

typedef short short8 __attribute__((ext_vector_type(8)));
typedef float f32x16 __attribute__((ext_vector_type(16)));

static __device__ __forceinline__ short f2b(float f) {
  __hip_bfloat16 h = __float2bfloat16(f);
  return __builtin_bit_cast(short, h);
}

// async global->LDS, 16B per lane; LDS dest = wave-uniform base + lane*16
static __device__ __forceinline__ void gload_lds16(const void* g, void* s) {
  __builtin_amdgcn_global_load_lds(
      (const __attribute__((address_space(1))) unsigned int*)g,
      (__attribute__((address_space(3))) unsigned int*)s, 16, 0, 0);
}

// ---- pack all 5 layers' w2(+b2 rows) into 32x32x16 B-fragment order ----
// window S = 16 k-rows; short8 at [S*128 + n*64 + l] holds
// B[S*16 + (l>>5)*8 + u][n*32 + (l&31)], n in {0,1}. One block = 32 rows = 2 S.
// Block 0 also zeroes the pool buffer.
__global__ __launch_bounds__(256) void k_pack_all(
    const float* __restrict__ w20, const float* __restrict__ b20,
    const float* __restrict__ w2c, const float* __restrict__ b2c,
    short* __restrict__ pk, float* __restrict__ gpool) {
  const int b = blockIdx.x, t = threadIdx.x;
  if (b == 0) { for (int i = t; i < N_GRAPHS * DIM; i += 256) gpool[i] = 0.f; }
  __shared__ float tile[32][65];
  const float *w2, *b2; short* out; int K, lb;
  if (b < 129) { w2 = w20; b2 = b20; out = pk; K = 4096; lb = b; }
  else {
    int bb = b - 129; int k = bb / 258; lb = bb % 258;
    w2 = w2c + (size_t)k * 8192 * 64; b2 = b2c + (size_t)k * 4096;
    out = pk + 264192 + (size_t)k * 528384; K = 8192;
  }
  #pragma unroll
  for (int it = 0; it < 2; ++it) {
    int idx = t + it * 256;
    int r = idx >> 4, c4 = idx & 15;
    int k = lb * 32 + r;
    const float* sp = (k < K) ? (w2 + (size_t)k * 64 + c4 * 4)
                              : (b2 + (size_t)(k - K) * 64 + c4 * 4);
    float4 v = *(const float4*)sp;
    float* dr = &tile[r][c4 * 4];
    dr[0] = v.x; dr[1] = v.y; dr[2] = v.z; dr[3] = v.w;
  }
  __syncthreads();
  const int S_local = t >> 7, n = (t >> 6) & 1, l = t & 63;
  const int rbase = S_local * 16 + ((l >> 5) << 3);
  const int col = n * 32 + (l & 31);
  short8 o;
  #pragma unroll
  for (int u = 0; u < 8; ++u) o[u] = f2b(tile[rbase + u][col]);
  ((short8*)out)[(size_t)lb * 256 + t] = o;
}

// ---- fused edge_feat + layer-0 edge MLP: block = 2 edges ----
__global__ __launch_bounds__(256) void k_ef_mlp1(
    const float* __restrict__ ea, const float* __restrict__ etw,
    const float* __restrict__ etb, const float* __restrict__ w1,
    const float* __restrict__ b1, float* __restrict__ e_feat,
    float* __restrict__ h1) {
  __shared__ float se[2][64];
  const int b = blockIdx.x, t = threadIdx.x;
  if (t < 128) {
    int el = t >> 6, o = t & 63;
    int e = b * 2 + el;
    float a = etb[o];
    const float* er = ea + (size_t)e * EDIM;
    #pragma unroll
    for (int i = 0; i < EDIM; ++i) a = fmaf(er[i], etw[i * 64 + o], a);
    se[el][o] = a;
    e_feat[(size_t)e * 64 + o] = a;
  }
  __syncthreads();
  {
    int el = t >> 7, j = t & 127;
    int e = b * 2 + el;
    float a = b1[j];
    #pragma unroll 8
    for (int i = 0; i < 64; ++i) a = fmaf(se[el][i], w1[i * 128 + j], a);
    h1[(size_t)e * 128 + j] = fmaxf(a, 0.f);
  }
}

// ---- layer-0 root init (reads x [N,32]); also zeroes part0 ----
__global__ __launch_bounds__(256) void k_root0(const float* __restrict__ x,
    const float* __restrict__ rootw, const float* __restrict__ rootb,
    float* __restrict__ agg, double* __restrict__ part0) {
  if (blockIdx.x == 0 && threadIdx.x < 128) part0[threadIdx.x] = 0.0;
  int idx = blockIdx.x * 256 + threadIdx.x;
  if (idx >= N_NODES * DIM) return;
  int n = idx >> 6, o = idx & 63;
  float a = rootb[o];
  const float* hr = x + (size_t)n * NFEAT;
  #pragma unroll 8
  for (int i = 0; i < NFEAT; ++i) a = fmaf(hr[i], rootw[i * 64 + o], a);
  agg[idx] = a;
}

// ---- implicit-A MFMA msg GEMM, 32x32x16, LDS-shared B ----
// msg[e,o] = sum_k A[e,k]B[k,o], A[e,j*IN+i] = h1[e,j]*x[src[e],i].
// Wave = 32 edges; block = 4 waves = 128 edges; grid.y = 8 K-chunks.
// B windows staged to LDS once per block (global_load_lds, dbuf,
// stage-after-barrier so the prefetch flies under compute).
template<int IN, int CHUNK>
__global__ __launch_bounds__(256, 3) void k_msg(
    const float* __restrict__ h1, const float* __restrict__ xin,
    const int* __restrict__ src, const int* __restrict__ dst,
    const short* __restrict__ pk, float* __restrict__ agg) {
  constexpr int QW = IN / 16;            // windows per j: 2 (L0) / 4
  constexpr int JR = CHUNK / IN;         // 16 j's per chunk
  constexpr int GBYTES = QW * 2048;      // bytes per j-group of B
  __shared__ float sh_h[128][JR + 1];
  __shared__ __align__(16) short bbuf[2][QW * 1024];
  const int t = threadIdx.x;
  const int l = t & 63;
  const int w = t >> 6;
  const int e0 = blockIdx.x * 128;
  const int jbase = blockIdx.y * JR;
  const int ng = JR + (blockIdx.y == 0 ? 1 : 0);   // +1 bias group on chunk 0

  const char* pkc = (const char*)pk;
  const char* bias_gb = pkc + (size_t)(8 * IN) * 2048;   // S = K/16

  auto stage = [&](int g) {
    const char* gb = (g < JR) ? pkc + (size_t)(jbase + g) * GBYTES : bias_gb;
    #pragma unroll
    for (int s = 0; s < QW / 2; ++s) {
      int off = w * (GBYTES / 4) + s * 1024;
      gload_lds16(gb + off + l * 16, (char*)&bbuf[g & 1][0] + off);
    }
  };

  // stage h1 tile [128][JR]
  {
    int row = t >> 1, half = t & 1;
    int e = e0 + row;
    const float* sp = h1 + (size_t)(e < N_EDGES ? e : 0) * 128 + jbase + half * 8;
    float4 v0 = ((const float4*)sp)[0];
    float4 v1 = ((const float4*)sp)[1];
    if (e >= N_EDGES) { v0 = float4{0,0,0,0}; v1 = float4{0,0,0,0}; }
    float* dr = &sh_h[row][half * 8];
    dr[0]=v0.x; dr[1]=v0.y; dr[2]=v0.z; dr[3]=v0.w;
    dr[4]=v1.x; dr[5]=v1.y; dr[6]=v1.z; dr[7]=v1.w;
  }
  stage(0);

  // x fragments: xr[q][u] = x[src[e]][q*16 + (l>>5)*8 + u]
  const int mrow = w * 32 + (l & 31);
  const int eme = e0 + mrow;
  const int srow = src[eme < N_EDGES ? eme : 0];
  const int h8 = (l >> 5) << 3;
  float xr[QW][8];
  #pragma unroll
  for (int q = 0; q < QW; ++q) {
    const float* xp = xin + (size_t)srow * IN + q * 16 + h8;
    float4 a = *(const float4*)xp;
    float4 b = *(const float4*)(xp + 4);
    xr[q][0]=a.x; xr[q][1]=a.y; xr[q][2]=a.z; xr[q][3]=a.w;
    xr[q][4]=b.x; xr[q][5]=b.y; xr[q][6]=b.z; xr[q][7]=b.w;
  }

  f32x16 acc0 = {}, acc1 = {};

  for (int g = 0; g < ng; ++g) {
    asm volatile("s_waitcnt vmcnt(0)" ::: "memory");  // stage(g) data landed
    __syncthreads();                                  // all waves' stages done
    if (g + 1 < ng) stage(g + 1);                     // prefetch flies under compute
    const short8* bp = (const short8*)&bbuf[g & 1][0];
    if (g < JR) {
      float hv = sh_h[mrow][g];
      #pragma unroll
      for (int q = 0; q < QW; ++q) {
        short8 b0 = bp[q * 128 + l];
        short8 b1 = bp[q * 128 + 64 + l];
        short8 av;
        #pragma unroll
        for (int u = 0; u < 8; ++u) av[u] = f2b(hv * xr[q][u]);
        acc0 = __builtin_amdgcn_mfma_f32_32x32x16_bf16(av, b0, acc0, 0, 0, 0);
        acc1 = __builtin_amdgcn_mfma_f32_32x32x16_bf16(av, b1, acc1, 0, 0, 0);
      }
    } else {  // bias rows: A = x directly
      #pragma unroll
      for (int q = 0; q < QW; ++q) {
        short8 b0 = bp[q * 128 + l];
        short8 b1 = bp[q * 128 + 64 + l];
        short8 av;
        #pragma unroll
        for (int u = 0; u < 8; ++u) av[u] = f2b(xr[q][u]);
        acc0 = __builtin_amdgcn_mfma_f32_32x32x16_bf16(av, b0, acc0, 0, 0, 0);
        acc1 = __builtin_amdgcn_mfma_f32_32x32x16_bf16(av, b1, acc1, 0, 0, 0);
      }
    }
  }

  // C/D (m74/m101): col = lane&31, row = (v&3) + 8*(v>>2) + 4*(lane>>5)
  #pragma unroll
  for (int v = 0; v < 16; ++v) {
    int r = (v & 3) + ((v >> 2) << 3) + ((l >> 5) << 2);
    int e2 = e0 + w * 32 + r;
    if (e2 < N_EDGES) {
      float* ap = agg + (size_t)dst[e2] * 64 + (l & 31);
      atomicAdd(ap, acc0[v]);
      atomicAdd(ap + 32, acc1[v]);
    }
  }
}

// ---- BN partial sums (coalesced, f64 atomics into part[0..127]) ----
__global__ __launch_bounds__(256) void k_bnpart(const float* __restrict__ agg,
    double* __restrict__ part) {
  const int t = threadIdx.x;
  const int c = t & 63, rg = t >> 6;
  const int r0 = blockIdx.x * 50;
  const int r1 = min(r0 + 50, N_NODES);
  double s = 0.0, s2 = 0.0;
  for (int r = r0 + rg; r < r1; r += 4) {
    float v = agg[(size_t)r * 64 + c];
    s += v;
    s2 += (double)v * v;
  }
  __shared__ double shs[4][64];
  __shared__ double shq[4][64];
  shs[rg][c] = s; shq[rg][c] = s2;
  __syncthreads();
  if (t < 64) {
    double ts = shs[0][t] + shs[1][t] + shs[2][t] + shs[3][t];
    double tq = shq[0][t] + shq[1][t] + shq[2][t] + shq[3][t];
    atomicAdd(&part[t], ts);
    atomicAdd(&part[64 + t], tq);
  }
}

// ---- fused: bnapply(k) [+resid] -> h_cur; root(k+1) -> agg; mlp1(k+1) -> h1;
//      zero next part buffer. Blocks [0,2500): bn+root; [2500,12500): mlp1. ----
__global__ __launch_bounds__(256) void k_inter(
    const float* agg, const double* __restrict__ part,
    const float* __restrict__ gamma, const float* __restrict__ beta,
    const float* resid, float* hout,
    const float* __restrict__ rootw, const float* __restrict__ rootb,
    float* aggn, double* __restrict__ partn,
    const float* __restrict__ ef, const float* __restrict__ w1,
    const float* __restrict__ b1, float* __restrict__ h1) {
  const int b = blockIdx.x, t = threadIdx.x;
  if (b < 2500) {
    __shared__ float sh[4][64];
    int idx = b * 256 + t;
    int c = t & 63, rl = t >> 6;
    float m = (float)(part[c] * (1.0 / N_NODES));
    float s2 = (float)(part[64 + c] * (1.0 / N_NODES));
    float inv = 1.0f / sqrtf(s2 - m * m + 1e-5f);
    float sc = gamma[c] * inv;
    float sf = beta[c] - m * sc;
    float v = fmaxf(fmaf(agg[idx], sc, sf), 0.f);
    if (resid) v += resid[idx];
    sh[rl][c] = v;
    hout[idx] = v;
    if (b == 0 && t < 128) partn[t] = 0.0;
    __syncthreads();
    float a = rootb[c];
    #pragma unroll 8
    for (int i = 0; i < 64; ++i) a = fmaf(sh[rl][i], rootw[i * 64 + c], a);
    aggn[idx] = a;
  } else {
    int idx = (b - 2500) * 256 + t;
    int e = idx >> 7, j = idx & 127;
    float a = b1[j];
    const float* er = ef + (size_t)e * 64;
    #pragma unroll 8
    for (int i = 0; i < 64; ++i) a = fmaf(er[i], w1[i * 128 + j], a);
    h1[idx] = fmaxf(a, 0.f);
  }
}

// ---- final layer: bnapply(4) + resid + global_max_pool (atomicMax on bits) ----
__global__ __launch_bounds__(256) void k_final(const float* __restrict__ agg,
    const double* __restrict__ part, const float* __restrict__ gamma,
    const float* __restrict__ beta, const float* __restrict__ resid,
    const int* __restrict__ batch, float* __restrict__ gpool) {
  int idx = blockIdx.x * 256 + threadIdx.x;
  if (idx >= N_NODES * DIM) return;
  int c = idx & 63, r = idx >> 6;
  float m = (float)(part[c] * (1.0 / N_NODES));
  float s2 = (float)(part[64 + c] * (1.0 / N_NODES));
  float inv = 1.0f / sqrtf(s2 - m * m + 1e-5f);
  float sc = gamma[c] * inv;
  float sf = beta[c] - m * sc;
  float v = fmaxf(fmaf(agg[idx], sc, sf), 0.f) + resid[idx];
  atomicMax((unsigned int*)&gpool[batch[r] * 64 + c], __float_as_uint(v));
}

// ---- head: per-graph row-local MLP chain; 64 blocks x 64 threads ----
__global__ __launch_bounds__(64) void k_head(const float* __restrict__ g,
    const float* __restrict__ w1, const float* __restrict__ b1,
    const float* __restrict__ w2, const float* __restrict__ b2,
    const float* __restrict__ wo, const float* __restrict__ bo,
    float* __restrict__ out) {
  __shared__ float s0[64];
  __shared__ float s1[64];
  const int r = blockIdx.x, t = threadIdx.x;
  s0[t] = g[r * 64 + t];
  __syncthreads();
  float a = b1[t];
  #pragma unroll 8
  for (int i = 0; i < 64; ++i) a = fmaf(s0[i], w1[i * 64 + t], a);
  s1[t] = fmaxf(a, 0.f);
  __syncthreads();
  a = b2[t];
  #pragma unroll 8
  for (int i = 0; i < 64; ++i) a = fmaf(s1[i], w2[i * 64 + t], a);
  __syncthreads();
  s0[t] = fmaxf(a, 0.f);
  __syncthreads();
  if (t < NCLS) {
    float o = bo[t];
    #pragma unroll 8
    for (int i = 0; i < 64; ++i) o = fmaf(s0[i], wo[i * NCLS + t], o);
    out[r * NCLS + t] = 1.f / (1.f + expf(-o));
  }
}

extern "C" void kernel_launch(void* const* d_in, const int* in_sizes, int n_in,
                              void* d_out, int out_size, void* d_ws, size_t ws_size,
                              hipStream_t stream) {
  const float* x          = (const float*)d_in[0];
  const int*   eidx       = (const int*)d_in[1];
  const float* eattr      = (const float*)d_in[2];
  const int*   batch      = (const int*)d_in[3];
  const float* et_w       = (const float*)d_in[4];
  const float* et_b       = (const float*)d_in[5];
  const float* nn1_w1     = (const float*)d_in[6];
  const float* nn1_b1     = (const float*)d_in[7];
  const float* nn1_w2     = (const float*)d_in[8];
  const float* nn1_b2     = (const float*)d_in[9];
  const float* root_in    = (const float*)d_in[10];
  const float* bias_in    = (const float*)d_in[11];
  const float* convs_w1   = (const float*)d_in[12];
  const float* convs_b1   = (const float*)d_in[13];
  const float* convs_w2   = (const float*)d_in[14];
  const float* convs_b2   = (const float*)d_in[15];
  const float* convs_root = (const float*)d_in[16];
  const float* convs_bias = (const float*)d_in[17];
  const float* bn_gamma   = (const float*)d_in[18];
  const float* bn_beta    = (const float*)d_in[19];
  const float* lin1_w     = (const float*)d_in[20];
  const float* lin1_b     = (const float*)d_in[21];
  const float* lin2_w     = (const float*)d_in[22];
  const float* lin2_b     = (const float*)d_in[23];
  const float* lout_w     = (const float*)d_in[24];
  const float* lout_b     = (const float*)d_in[25];

  const int* srcp = eidx;
  const int* dstp = eidx + N_EDGES;

  double* part0 = (double*)d_ws;             // 128 doubles
  double* part1 = part0 + 128;               // 128 doubles
  float* e_feat = (float*)(part0 + 256);     // E*64
  float* h1     = e_feat + N_EDGES * DIM;    // E*128
  float* agg    = h1 + N_EDGES * 128;        // N*64
  float* h_cur  = agg + N_NODES * DIM;       // N*64
  float* g      = h_cur + N_NODES * DIM;     // 64*64
  short* pk0    = (short*)(g + N_GRAPHS * DIM);
  short* pkL[4];
  for (int k = 0; k < 4; ++k) pkL[k] = pk0 + 264192 + (size_t)k * 528384;
  double* parts[2] = {part0, part1};

  const dim3 gMsg(157, 8);

  k_pack_all<<<1161, 256, 0, stream>>>(nn1_w2, nn1_b2, convs_w2, convs_b2, pk0, g);
  k_ef_mlp1<<<N_EDGES / 2, 256, 0, stream>>>(eattr, et_w, et_b, nn1_w1, nn1_b1,
                                             e_feat, h1);
  k_root0<<<2500, 256, 0, stream>>>(x, root_in, bias_in, agg, part0);

  // layer 0
  k_msg<NFEAT, 512><<<gMsg, 256, 0, stream>>>(h1, x, srcp, dstp, pk0, agg);
  k_bnpart<<<200, 256, 0, stream>>>(agg, part0);

  for (int k = 0; k < 4; ++k) {
    // bnapply(layer k) + root(conv k) + mlp1(conv k) + zero part[(k+1)&1]
    k_inter<<<12500, 256, 0, stream>>>(
        agg, parts[k & 1], bn_gamma + k * 64, bn_beta + k * 64,
        (k == 0) ? nullptr : h_cur, h_cur,
        convs_root + (size_t)k * 4096, convs_bias + (size_t)k * 64,
        agg, parts[(k + 1) & 1],
        e_feat, convs_w1 + (size_t)k * 64 * 128, convs_b1 + (size_t)k * 128, h1);
    k_msg<DIM, 1024><<<gMsg, 256, 0, stream>>>(h1, h_cur, srcp, dstp, pkL[k], agg);
    k_bnpart<<<200, 256, 0, stream>>>(agg, parts[(k + 1) & 1]);
  }

  // conv3's bnpart wrote parts[(3+1)&1] = parts[0]  (R4 bug: read parts[1])
  k_final<<<2500, 256, 0, stream>>>(agg, parts[0], bn_gamma + 4 * 64,
                                    bn_beta + 4 * 64, h_cur, batch, g);
  k_head<<<N_GRAPHS, 64, 0, stream>>>(g, lin1_w, lin1_b, lin2_w, lin2_b,
                                      lout_w, lout_b, (float*)d_out);
}

// Round 6
// 444.648 us; speedup vs baseline: 5.8533x; 1.3268x over previous
//
#include <hip/hip_runtime.h>
#include <hip/hip_bf16.h>
#include <math.h>

#define N_NODES 10000
#define N_EDGES 20000
#define EPAD 20224
#define N_GRAPHS 64
#define DIM 64
#define NFEAT 32
#define EDIM 16
#define NCLS 10

typedef short short8 __attribute__((ext_vector_type(8)));
typedef float f32x16 __attribute__((ext_vector_type(16)));

static __device__ __forceinline__ short f2b(float f) {
  __hip_bfloat16 h = __float2bfloat16(f);
  return __builtin_bit_cast(short, h);
}

// async global->LDS, 16B per lane; LDS dest = wave-uniform base + lane*16
static __device__ __forceinline__ void gload_lds16(const void* g, void* s) {
  __builtin_amdgcn_global_load_lds(
      (const __attribute__((address_space(1))) unsigned int*)g,
      (__attribute__((address_space(3))) unsigned int*)s, 16, 0, 0);
}

// ---- pack all 5 layers' w2(+b2 rows) into 32x32x16 B-fragment order ----
__global__ __launch_bounds__(256) void k_pack_all(
    const float* __restrict__ w20, const float* __restrict__ b20,
    const float* __restrict__ w2c, const float* __restrict__ b2c,
    short* __restrict__ pk, float* __restrict__ gpool) {
  const int b = blockIdx.x, t = threadIdx.x;
  if (b == 0) { for (int i = t; i < N_GRAPHS * DIM; i += 256) gpool[i] = 0.f; }
  __shared__ float tile[32][65];
  const float *w2, *b2; short* out; int K, lb;
  if (b < 129) { w2 = w20; b2 = b20; out = pk; K = 4096; lb = b; }
  else {
    int bb = b - 129; int k = bb / 258; lb = bb % 258;
    w2 = w2c + (size_t)k * 8192 * 64; b2 = b2c + (size_t)k * 4096;
    out = pk + 264192 + (size_t)k * 528384; K = 8192;
  }
  #pragma unroll
  for (int it = 0; it < 2; ++it) {
    int idx = t + it * 256;
    int r = idx >> 4, c4 = idx & 15;
    int k = lb * 32 + r;
    const float* sp = (k < K) ? (w2 + (size_t)k * 64 + c4 * 4)
                              : (b2 + (size_t)(k - K) * 64 + c4 * 4);
    float4 v = *(const float4*)sp;
    float* dr = &tile[r][c4 * 4];
    dr[0] = v.x; dr[1] = v.y; dr[2] = v.z; dr[3] = v.w;
  }
  __syncthreads();
  const int S_local = t >> 7, n = (t >> 6) & 1, l = t & 63;
  const int rbase = S_local * 16 + ((l >> 5) << 3);
  const int col = n * 32 + (l & 31);
  short8 o;
  #pragma unroll
  for (int u = 0; u < 8; ++u) o[u] = f2b(tile[rbase + u][col]);
  ((short8*)out)[(size_t)lb * 256 + t] = o;
}

// ---- fused edge_feat + layer-0 edge MLP: block = 8 edges, LDS-tiled ----
__global__ __launch_bounds__(256) void k_ef_mlp1(
    const float* __restrict__ ea, const float* __restrict__ etw,
    const float* __restrict__ etb, const float* __restrict__ w1,
    const float* __restrict__ b1, float* __restrict__ e_feat,
    float* __restrict__ h1) {
  __shared__ float sea[8][17];
  __shared__ float se[8][65];
  const int b = blockIdx.x, t = threadIdx.x;
  const int e0 = b * 8;
  if (t < 128) {
    int r = t >> 4, c = t & 15;
    sea[r][c] = ea[(size_t)(e0 + r) * EDIM + c];
  }
  __syncthreads();
  {
    int o = t & 63, eh = t >> 6;
    #pragma unroll
    for (int k = 0; k < 2; ++k) {
      int r = eh * 2 + k;
      float a = etb[o];
      #pragma unroll
      for (int i = 0; i < EDIM; ++i) a = fmaf(sea[r][i], etw[i * 64 + o], a);
      se[r][o] = a;
      e_feat[(size_t)(e0 + r) * 64 + o] = a;
    }
  }
  __syncthreads();
  {
    int j = t & 127, eh = t >> 7;
    int r0 = eh * 4;
    float a0 = b1[j], a1 = a0, a2 = a0, a3 = a0;
    #pragma unroll 8
    for (int i = 0; i < 64; ++i) {
      float wv = w1[i * 128 + j];
      a0 = fmaf(se[r0 + 0][i], wv, a0);
      a1 = fmaf(se[r0 + 1][i], wv, a1);
      a2 = fmaf(se[r0 + 2][i], wv, a2);
      a3 = fmaf(se[r0 + 3][i], wv, a3);
    }
    size_t base = (size_t)(e0 + r0) * 128 + j;
    h1[base +   0] = fmaxf(a0, 0.f);
    h1[base + 128] = fmaxf(a1, 0.f);
    h1[base + 256] = fmaxf(a2, 0.f);
    h1[base + 384] = fmaxf(a3, 0.f);
  }
}

// ---- layer-0 root init; also zeroes part0 ----
__global__ __launch_bounds__(256) void k_root0(const float* __restrict__ x,
    const float* __restrict__ rootw, const float* __restrict__ rootb,
    float* __restrict__ agg, double* __restrict__ part0) {
  if (blockIdx.x == 0 && threadIdx.x < 128) part0[threadIdx.x] = 0.0;
  int idx = blockIdx.x * 256 + threadIdx.x;
  if (idx >= N_NODES * DIM) return;
  int n = idx >> 6, o = idx & 63;
  float a = rootb[o];
  const float* hr = x + (size_t)n * NFEAT;
  #pragma unroll 8
  for (int i = 0; i < NFEAT; ++i) a = fmaf(hr[i], rootw[i * 64 + o], a);
  agg[idx] = a;
}

// ---- implicit-A MFMA msg GEMM, 32x32x16, LDS-shared B, M=64/wave ----
// Writes per-chunk partials (plain stores) to pt[chunk][EPAD][64].
template<int IN>
__global__ __launch_bounds__(256, 2) void k_msg(
    const float* __restrict__ h1, const float* __restrict__ xin,
    const int* __restrict__ src, const short* __restrict__ pk,
    float* __restrict__ pt) {
  constexpr int QW = IN / 16;            // B windows per j: 2 (L0) / 4
  constexpr int JR = 32;                 // j's per chunk
  constexpr int GBYTES = QW * 2048;      // B bytes per j-group
  __shared__ float sh_h[256][JR + 1];
  __shared__ __align__(16) short bbuf[2][QW * 1024];
  const int t = threadIdx.x, l = t & 63, w = t >> 6;
  const int e0 = blockIdx.x * 256;
  const int jbase = blockIdx.y * JR;
  const int ng = JR + (blockIdx.y == 0 ? 1 : 0);   // +1 bias group on chunk 0

  const char* pkc = (const char*)pk;
  const char* bias_gb = pkc + (size_t)(8 * IN) * 2048;

  auto stage = [&](int g) {
    const char* gb = (g < JR) ? pkc + (size_t)(jbase + g) * GBYTES : bias_gb;
    #pragma unroll
    for (int s = 0; s < QW / 2; ++s) {
      int off = w * (GBYTES / 4) + s * 1024;
      gload_lds16(gb + off + l * 16, (char*)&bbuf[g & 1][0] + off);
    }
  };

  // stage h1 tile [256][32]
  #pragma unroll
  for (int it = 0; it < 8; ++it) {
    int idx = t + it * 256;
    int row = idx >> 3, c4 = idx & 7;
    int e = e0 + row;
    float4 v = {0.f, 0.f, 0.f, 0.f};
    if (e < N_EDGES) v = *(const float4*)(h1 + (size_t)e * 128 + jbase + c4 * 4);
    float* dr = &sh_h[row][c4 * 4];
    dr[0] = v.x; dr[1] = v.y; dr[2] = v.z; dr[3] = v.w;
  }
  stage(0);

  // x fragments for both M-subtiles (live whole K-loop)
  const int h8 = (l >> 5) << 3;
  float xr[2][QW][8];
  #pragma unroll
  for (int m = 0; m < 2; ++m) {
    int eme = e0 + w * 64 + m * 32 + (l & 31);
    int srow = src[eme < N_EDGES ? eme : 0];
    #pragma unroll
    for (int q = 0; q < QW; ++q) {
      const float* xp = xin + (size_t)srow * IN + q * 16 + h8;
      float4 a = *(const float4*)xp;
      float4 bq = *(const float4*)(xp + 4);
      xr[m][q][0] = a.x;  xr[m][q][1] = a.y;  xr[m][q][2] = a.z;  xr[m][q][3] = a.w;
      xr[m][q][4] = bq.x; xr[m][q][5] = bq.y; xr[m][q][6] = bq.z; xr[m][q][7] = bq.w;
    }
  }

  f32x16 acc00 = {}, acc01 = {}, acc10 = {}, acc11 = {};

  for (int g = 0; g < ng; ++g) {
    asm volatile("s_waitcnt vmcnt(0)" ::: "memory");  // stage(g) landed
    __syncthreads();                                  // all writes visible
    if (g + 1 < ng) stage(g + 1);                     // prefetch under compute
    const short8* bp = (const short8*)&bbuf[g & 1][0];
    if (g < JR) {
      float hv0 = sh_h[w * 64 + (l & 31)][g];
      float hv1 = sh_h[w * 64 + 32 + (l & 31)][g];
      #pragma unroll
      for (int q = 0; q < QW; ++q) {
        short8 b0 = bp[q * 128 + l];
        short8 b1 = bp[q * 128 + 64 + l];
        short8 av0, av1;
        #pragma unroll
        for (int u = 0; u < 8; ++u) {
          av0[u] = f2b(hv0 * xr[0][q][u]);
          av1[u] = f2b(hv1 * xr[1][q][u]);
        }
        acc00 = __builtin_amdgcn_mfma_f32_32x32x16_bf16(av0, b0, acc00, 0, 0, 0);
        acc01 = __builtin_amdgcn_mfma_f32_32x32x16_bf16(av0, b1, acc01, 0, 0, 0);
        acc10 = __builtin_amdgcn_mfma_f32_32x32x16_bf16(av1, b0, acc10, 0, 0, 0);
        acc11 = __builtin_amdgcn_mfma_f32_32x32x16_bf16(av1, b1, acc11, 0, 0, 0);
      }
    } else {  // bias rows: A = x directly
      #pragma unroll
      for (int q = 0; q < QW; ++q) {
        short8 b0 = bp[q * 128 + l];
        short8 b1 = bp[q * 128 + 64 + l];
        short8 av0, av1;
        #pragma unroll
        for (int u = 0; u < 8; ++u) {
          av0[u] = f2b(xr[0][q][u]);
          av1[u] = f2b(xr[1][q][u]);
        }
        acc00 = __builtin_amdgcn_mfma_f32_32x32x16_bf16(av0, b0, acc00, 0, 0, 0);
        acc01 = __builtin_amdgcn_mfma_f32_32x32x16_bf16(av0, b1, acc01, 0, 0, 0);
        acc10 = __builtin_amdgcn_mfma_f32_32x32x16_bf16(av1, b0, acc10, 0, 0, 0);
        acc11 = __builtin_amdgcn_mfma_f32_32x32x16_bf16(av1, b1, acc11, 0, 0, 0);
      }
    }
  }

  // C/D (m74/m101): col = lane&31, row = (v&3)+8*(v>>2)+4*(lane>>5); plain stores
  float* po = pt + ((size_t)blockIdx.y * EPAD + e0 + w * 64) * 64 + (l & 31);
  #pragma unroll
  for (int v = 0; v < 16; ++v) {
    int r = (v & 3) + ((v >> 2) << 3) + ((l >> 5) << 2);
    po[(size_t)r * 64]             = acc00[v];
    po[(size_t)r * 64 + 32]       = acc01[v];
    po[(size_t)(r + 32) * 64]      = acc10[v];
    po[(size_t)(r + 32) * 64 + 32] = acc11[v];
  }
}

// ---- sum 4 chunk-partials, single atomicAdd per output element ----
__global__ __launch_bounds__(256) void k_reduce(const float* __restrict__ pt,
    const int* __restrict__ dst, float* __restrict__ agg) {
  int idx = blockIdx.x * 256 + threadIdx.x;
  int e = idx >> 4;
  if (e >= N_EDGES) return;
  int c = (idx & 15) * 4;
  const float* p = pt + (size_t)e * 64 + c;
  float4 s0 = *(const float4*)p;
  float4 s1 = *(const float4*)(p + (size_t)EPAD * 64);
  float4 s2 = *(const float4*)(p + (size_t)2 * EPAD * 64);
  float4 s3 = *(const float4*)(p + (size_t)3 * EPAD * 64);
  float* ap = agg + (size_t)dst[e] * 64 + c;
  atomicAdd(ap + 0, s0.x + s1.x + s2.x + s3.x);
  atomicAdd(ap + 1, s0.y + s1.y + s2.y + s3.y);
  atomicAdd(ap + 2, s0.z + s1.z + s2.z + s3.z);
  atomicAdd(ap + 3, s0.w + s1.w + s2.w + s3.w);
}

// ---- BN partial sums (coalesced, f64 atomics into part[0..127]) ----
__global__ __launch_bounds__(256) void k_bnpart(const float* __restrict__ agg,
    double* __restrict__ part) {
  const int t = threadIdx.x;
  const int c = t & 63, rg = t >> 6;
  const int r0 = blockIdx.x * 50;
  const int r1 = min(r0 + 50, N_NODES);
  double s = 0.0, s2 = 0.0;
  for (int r = r0 + rg; r < r1; r += 4) {
    float v = agg[(size_t)r * 64 + c];
    s += v;
    s2 += (double)v * v;
  }
  __shared__ double shs[4][64];
  __shared__ double shq[4][64];
  shs[rg][c] = s; shq[rg][c] = s2;
  __syncthreads();
  if (t < 64) {
    double ts = shs[0][t] + shs[1][t] + shs[2][t] + shs[3][t];
    double tq = shq[0][t] + shq[1][t] + shq[2][t] + shq[3][t];
    atomicAdd(&part[t], ts);
    atomicAdd(&part[64 + t], tq);
  }
}

// ---- fused: bnapply(k)[+resid]->h_cur; root(k+1)->agg; mlp1(k+1)->h1 ----
// blocks [0,157): bn+root for 64 nodes; [157,2657): mlp1 for 8 edges.
__global__ __launch_bounds__(256) void k_inter(
    const float* __restrict__ agg, const double* __restrict__ part,
    const float* __restrict__ gamma, const float* __restrict__ beta,
    const float* resid, float* __restrict__ hout,
    const float* __restrict__ rootw, const float* __restrict__ rootb,
    float* __restrict__ aggn, double* __restrict__ partn,
    const float* __restrict__ ef, const float* __restrict__ w1,
    const float* __restrict__ b1, float* __restrict__ h1) {
  const int b = blockIdx.x, t = threadIdx.x;
  if (b < 157) {
    __shared__ float sh[64][65];
    if (b == 0 && t < 128) partn[t] = 0.0;
    const int o = t & 63, rg = t >> 6;
    const int n0 = b * 64;
    float m = (float)(part[o] * (1.0 / N_NODES));
    float s2 = (float)(part[64 + o] * (1.0 / N_NODES));
    float inv = 1.0f / sqrtf(s2 - m * m + 1e-5f);
    float sc = gamma[o] * inv;
    float sf = beta[o] - m * sc;
    #pragma unroll
    for (int k = 0; k < 16; ++k) {
      int r = rg * 16 + k;
      int n = n0 + r;
      float v = 0.f;
      if (n < N_NODES) {
        v = fmaxf(fmaf(agg[(size_t)n * 64 + o], sc, sf), 0.f);
        if (resid) v += resid[(size_t)n * 64 + o];
        hout[(size_t)n * 64 + o] = v;
      }
      sh[r][o] = v;
    }
    __syncthreads();
    float acc[16];
    float rb = rootb[o];
    #pragma unroll
    for (int k = 0; k < 16; ++k) acc[k] = rb;
    for (int i = 0; i < 64; ++i) {
      float wv = rootw[i * 64 + o];
      #pragma unroll
      for (int k = 0; k < 16; ++k) acc[k] = fmaf(sh[rg * 16 + k][i], wv, acc[k]);
    }
    #pragma unroll
    for (int k = 0; k < 16; ++k) {
      int n = n0 + rg * 16 + k;
      if (n < N_NODES) aggn[(size_t)n * 64 + o] = acc[k];
    }
  } else {
    const int e0 = (b - 157) * 8;
    __shared__ float se[8][65];
    {
      int r = t >> 5, ci = (t & 31) * 2;
      const float* sp = ef + (size_t)(e0 + r) * 64 + ci;
      se[r][ci] = sp[0];
      se[r][ci + 1] = sp[1];
    }
    __syncthreads();
    const int j = t & 127, eh = t >> 7;
    const int r0 = eh * 4;
    float a0 = b1[j], a1 = a0, a2 = a0, a3 = a0;
    #pragma unroll 8
    for (int i = 0; i < 64; ++i) {
      float wv = w1[i * 128 + j];
      a0 = fmaf(se[r0 + 0][i], wv, a0);
      a1 = fmaf(se[r0 + 1][i], wv, a1);
      a2 = fmaf(se[r0 + 2][i], wv, a2);
      a3 = fmaf(se[r0 + 3][i], wv, a3);
    }
    size_t base = (size_t)(e0 + r0) * 128 + j;
    h1[base +   0] = fmaxf(a0, 0.f);
    h1[base + 128] = fmaxf(a1, 0.f);
    h1[base + 256] = fmaxf(a2, 0.f);
    h1[base + 384] = fmaxf(a3, 0.f);
  }
}

// ---- final: bnapply(4) + resid + global_max_pool ----
__global__ __launch_bounds__(256) void k_final(const float* __restrict__ agg,
    const double* __restrict__ part, const float* __restrict__ gamma,
    const float* __restrict__ beta, const float* __restrict__ resid,
    const int* __restrict__ batch, float* __restrict__ gpool) {
  int idx = blockIdx.x * 256 + threadIdx.x;
  if (idx >= N_NODES * DIM) return;
  int c = idx & 63, r = idx >> 6;
  float m = (float)(part[c] * (1.0 / N_NODES));
  float s2 = (float)(part[64 + c] * (1.0 / N_NODES));
  float inv = 1.0f / sqrtf(s2 - m * m + 1e-5f);
  float sc = gamma[c] * inv;
  float sf = beta[c] - m * sc;
  float v = fmaxf(fmaf(agg[idx], sc, sf), 0.f) + resid[idx];
  atomicMax((unsigned int*)&gpool[batch[r] * 64 + c], __float_as_uint(v));
}

// ---- head: per-graph MLP chain ----
__global__ __launch_bounds__(64) void k_head(const float* __restrict__ g,
    const float* __restrict__ w1, const float* __restrict__ b1,
    const float* __restrict__ w2, const float* __restrict__ b2,
    const float* __restrict__ wo, const float* __restrict__ bo,
    float* __restrict__ out) {
  __shared__ float s0[64];
  __shared__ float s1[64];
  const int r = blockIdx.x, t = threadIdx.x;
  s0[t] = g[r * 64 + t];
  __syncthreads();
  float a = b1[t];
  #pragma unroll 8
  for (int i = 0; i < 64; ++i) a = fmaf(s0[i], w1[i * 64 + t], a);
  s1[t] = fmaxf(a, 0.f);
  __syncthreads();
  a = b2[t];
  #pragma unroll 8
  for (int i = 0; i < 64; ++i) a = fmaf(s1[i], w2[i * 64 + t], a);
  __syncthreads();
  s0[t] = fmaxf(a, 0.f);
  __syncthreads();
  if (t < NCLS) {
    float o = bo[t];
    #pragma unroll 8
    for (int i = 0; i < 64; ++i) o = fmaf(s0[i], wo[i * NCLS + t], o);
    out[r * NCLS + t] = 1.f / (1.f + expf(-o));
  }
}

extern "C" void kernel_launch(void* const* d_in, const int* in_sizes, int n_in,
                              void* d_out, int out_size, void* d_ws, size_t ws_size,
                              hipStream_t stream) {
  const float* x          = (const float*)d_in[0];
  const int*   eidx       = (const int*)d_in[1];
  const float* eattr      = (const float*)d_in[2];
  const int*   batch      = (const int*)d_in[3];
  const float* et_w       = (const float*)d_in[4];
  const float* et_b       = (const float*)d_in[5];
  const float* nn1_w1     = (const float*)d_in[6];
  const float* nn1_b1     = (const float*)d_in[7];
  const float* nn1_w2     = (const float*)d_in[8];
  const float* nn1_b2     = (const float*)d_in[9];
  const float* root_in    = (const float*)d_in[10];
  const float* bias_in    = (const float*)d_in[11];
  const float* convs_w1   = (const float*)d_in[12];
  const float* convs_b1   = (const float*)d_in[13];
  const float* convs_w2   = (const float*)d_in[14];
  const float* convs_b2   = (const float*)d_in[15];
  const float* convs_root = (const float*)d_in[16];
  const float* convs_bias = (const float*)d_in[17];
  const float* bn_gamma   = (const float*)d_in[18];
  const float* bn_beta    = (const float*)d_in[19];
  const float* lin1_w     = (const float*)d_in[20];
  const float* lin1_b     = (const float*)d_in[21];
  const float* lin2_w     = (const float*)d_in[22];
  const float* lin2_b     = (const float*)d_in[23];
  const float* lout_w     = (const float*)d_in[24];
  const float* lout_b     = (const float*)d_in[25];

  const int* srcp = eidx;
  const int* dstp = eidx + N_EDGES;

  double* part0 = (double*)d_ws;             // 128 doubles
  double* part1 = part0 + 128;               // 128 doubles
  float* e_feat = (float*)(part0 + 256);     // E*64
  float* h1     = e_feat + N_EDGES * DIM;    // E*128
  float* agg    = h1 + N_EDGES * 128;        // N*64
  float* h_cur  = agg + N_NODES * DIM;       // N*64
  float* g      = h_cur + N_NODES * DIM;     // 64*64
  short* pk0    = (short*)(g + N_GRAPHS * DIM);
  short* pkL[4];
  for (int k = 0; k < 4; ++k) pkL[k] = pk0 + 264192 + (size_t)k * 528384;
  float* pt     = (float*)(pk0 + 264192 + 4 * 528384);  // 4*EPAD*64 f32
  double* parts[2] = {part0, part1};

  const dim3 gMsg(79, 4);
  const int gRed = EPAD * 16 / 256;   // 1264

  k_pack_all<<<1161, 256, 0, stream>>>(nn1_w2, nn1_b2, convs_w2, convs_b2, pk0, g);
  k_ef_mlp1<<<2500, 256, 0, stream>>>(eattr, et_w, et_b, nn1_w1, nn1_b1,
                                      e_feat, h1);
  k_root0<<<2500, 256, 0, stream>>>(x, root_in, bias_in, agg, part0);

  // layer 0
  k_msg<NFEAT><<<gMsg, 256, 0, stream>>>(h1, x, srcp, pk0, pt);
  k_reduce<<<gRed, 256, 0, stream>>>(pt, dstp, agg);
  k_bnpart<<<200, 256, 0, stream>>>(agg, part0);

  for (int k = 0; k < 4; ++k) {
    k_inter<<<2657, 256, 0, stream>>>(
        agg, parts[k & 1], bn_gamma + k * 64, bn_beta + k * 64,
        (k == 0) ? nullptr : h_cur, h_cur,
        convs_root + (size_t)k * 4096, convs_bias + (size_t)k * 64,
        agg, parts[(k + 1) & 1],
        e_feat, convs_w1 + (size_t)k * 64 * 128, convs_b1 + (size_t)k * 128, h1);
    k_msg<DIM><<<gMsg, 256, 0, stream>>>(h1, h_cur, srcp, pkL[k], pt);
    k_reduce<<<gRed, 256, 0, stream>>>(pt, dstp, agg);
    k_bnpart<<<200, 256, 0, stream>>>(agg, parts[(k + 1) & 1]);
  }

  k_final<<<2500, 256, 0, stream>>>(agg, parts[0], bn_gamma + 4 * 64,
                                    bn_beta + 4 * 64, h_cur, batch, g);
  k_head<<<N_GRAPHS, 64, 0, stream>>>(g, lin1_w, lin1_b, lin2_w, lin2_b,
                                      lout_w, lout_b, (float*)d_out);
}